// Round 9
// baseline (53.737 us; speedup 1.0000x reference)
//
#include <hip/hip_runtime.h>
#include <hip/hip_bf16.h>

#define B_ 2
#define S_ 1024
#define E_ 128
#define H_ 4
#define D_ 32
#define BHSD (B_ * H_ * S_ * D_)   // 262144 floats per tensor
#define LOG2E 1.44269504088896f

// ---------------------------------------------------------------------------
// Kernel A: fused QKV projection (validated R5/R8 version).
//   Q and K pre-scaled by log2(e) so attention uses bare exp2.
// ---------------------------------------------------------------------------
__global__ __launch_bounds__(128) void qkv_kernel(
    const float* __restrict__ x,
    const float* __restrict__ Wq, const float* __restrict__ bq,
    const float* __restrict__ Wk, const float* __restrict__ bk,
    const float* __restrict__ Wv, const float* __restrict__ bv,
    float* __restrict__ ws) {
  const int mat = blockIdx.y;
  const float* W    = (mat == 0) ? Wq : (mat == 1) ? Wk : Wv;
  const float* bias = (mat == 0) ? bq : (mat == 1) ? bk : bv;
  const float scale = (mat == 2) ? 1.0f : LOG2E;
  float* outbase = ws + (size_t)mat * BHSD;

  const int row0 = blockIdx.x * 8;
  const int t = threadIdx.x;

  __shared__ __align__(16) float xs[8 * E_];
  const float4* xg = (const float4*)(x + (size_t)row0 * E_);
  float4* xs4 = (float4*)xs;
  #pragma unroll
  for (int i = 0; i < 2; ++i) xs4[t + i * 128] = xg[t + i * 128];
  __syncthreads();

  const int col = t;
  const float4* W4 = (const float4*)(W + (size_t)col * E_);

  float acc[8];
  #pragma unroll
  for (int r = 0; r < 8; ++r) acc[r] = 0.f;

  #pragma unroll 4
  for (int c4 = 0; c4 < E_ / 4; ++c4) {
    float4 w = W4[c4];
    #pragma unroll
    for (int r = 0; r < 8; ++r) {
      float4 xv = xs4[r * (E_ / 4) + c4];
      acc[r] += xv.x * w.x + xv.y * w.y + xv.z * w.z + xv.w * w.w;
    }
  }

  const float bcol = bias[col];
  const int h = col >> 5, d = col & 31;
  #pragma unroll
  for (int r = 0; r < 8; ++r) {
    int row = row0 + r;
    int b = row >> 10, s = row & 1023;
    outbase[(((size_t)(b * H_ + h)) * S_ + s) * D_ + d] = (acc[r] + bcol) * scale;
  }
}

// ---------------------------------------------------------------------------
// Kernel B: ultrametric attention as two register-tiled "GEMMs" (32-row block).
//   Block = 32 Q-rows x 256 keys (kc chunk), 256 threads (4 waves).
//   Per 64-key iteration (2 barriers only — P is wave-private):
//     stage K/V tile -> barrier
//     DIST: wave w keys [w*16,+16); lane (rg=lane>>3, kg=lane&7) owns
//           4 rows {rg+8i} x 2 keys {w*16+kg+8j}; dist[4][2] over 8 d-chunks.
//     p = exp2(-dist); P written transposed to Ps[key][rg*4+i] —
//           rows [w*16,+16) are written AND read by wave w only (wave-private;
//           same-wave LDS RAW ordered by lgkmcnt, no barrier needed).
//     PV:   lane (rg, kg): O[4 rows][4 dims {kg*4..}]; 16 keys; b128 reads.
//     barrier (protects next stage overwrite of Ks/Vs).
//   LDS 31.5 KB -> 5 blocks/CU LDS-limit; grid 1024 = 4 blocks/CU.
// grid = 8 heads * 32 rowtiles * 4 kc = 1024 blocks.
// ---------------------------------------------------------------------------
#define QSTRIDE 36

__global__ __launch_bounds__(256) void attn_kernel(
    const float* __restrict__ qg, const float* __restrict__ kg_,
    const float* __restrict__ vg,
    float* __restrict__ part_o, float* __restrict__ part_l) {
  __shared__ __align__(16) float Qs[32 * QSTRIDE];   // 4608 B
  __shared__ __align__(16) float Ks[64 * QSTRIDE];   // 9216 B
  __shared__ __align__(16) float Vs[64 * QSTRIDE];   // 9216 B
  __shared__ __align__(16) float Ps[64 * QSTRIDE];   // 9216 B (l-merge reuses head)

  const int bx = blockIdx.x;
  const int kc   = bx & 3;
  const int rt   = bx >> 2;            // 0..255 : (head, rowtile)
  const int head = rt >> 5;            // b*H + h, 0..7
  const int rtl  = rt & 31;            // row tile within head (32 rows each)
  const int t = threadIdx.x;
  const int w = t >> 6;                // wave 0..3
  const int lane = t & 63;
  const int rg = lane >> 3;            // row group: rows {rg + 8i, i<4}
  const int kg = lane & 7;             // key group (DIST) / dim group (PV)

  const float* qbase = qg  + (size_t)head * S_ * D_ + (size_t)rtl * 32 * D_;
  const float* kbase = kg_ + (size_t)head * S_ * D_ + (size_t)kc * 256 * D_;
  const float* vbase = vg  + (size_t)head * S_ * D_ + (size_t)kc * 256 * D_;

  // ---- stage Q tile once: 32x32 = 256 float4 (1 per thread) ----
  {
    const float4* src = (const float4*)qbase;
    int rr = t >> 3, c4 = t & 7;
    *(float4*)(Qs + rr * QSTRIDE + c4 * 4) = src[t];
  }

  float O[4][4];
  #pragma unroll
  for (int i = 0; i < 4; ++i)
    #pragma unroll
    for (int c = 0; c < 4; ++c) O[i][c] = 0.f;
  float lrow[4];
  #pragma unroll
  for (int i = 0; i < 4; ++i) lrow[i] = 0.f;

  for (int it = 0; it < 4; ++it) {
    // ---- stage K,V 64-key tiles: 512 float4 each, 2 per thread ----
    {
      const float4* ksrc = (const float4*)(kbase + (size_t)it * 64 * D_);
      const float4* vsrc = (const float4*)(vbase + (size_t)it * 64 * D_);
      #pragma unroll
      for (int i = 0; i < 2; ++i) {
        int f = t + i * 256;
        int rr = f >> 3, c4 = f & 7;
        *(float4*)(Ks + rr * QSTRIDE + c4 * 4) = ksrc[f];
        *(float4*)(Vs + rr * QSTRIDE + c4 * 4) = vsrc[f];
      }
    }
    __syncthreads();

    // ---- DIST: dist[4 rows][2 keys] over 8 d-chunks ----
    float dist[4][2];
    #pragma unroll
    for (int i = 0; i < 4; ++i) { dist[i][0] = 0.f; dist[i][1] = 0.f; }

    #pragma unroll
    for (int c = 0; c < 8; ++c) {
      float4 qv[4];
      #pragma unroll
      for (int i = 0; i < 4; ++i)
        qv[i] = *(const float4*)(Qs + (rg + 8 * i) * QSTRIDE + c * 4);
      float4 kv[2];
      #pragma unroll
      for (int j = 0; j < 2; ++j)
        kv[j] = *(const float4*)(Ks + (w * 16 + kg + 8 * j) * QSTRIDE + c * 4);
      #pragma unroll
      for (int i = 0; i < 4; ++i) {
        #pragma unroll
        for (int j = 0; j < 2; ++j) {
          float m0 = fmaxf(fabsf(qv[i].x - kv[j].x), fabsf(qv[i].y - kv[j].y));
          float m1 = fmaxf(fabsf(qv[i].z - kv[j].z), fabsf(qv[i].w - kv[j].w));
          dist[i][j] = fmaxf(dist[i][j], fmaxf(m0, m1));
        }
      }
    }

    // ---- p = exp2(-dist); accumulate l; write P transposed (wave-private) --
    float pp[4][2];
    #pragma unroll
    for (int i = 0; i < 4; ++i) {
      #pragma unroll
      for (int j = 0; j < 2; ++j) {
        float p = exp2f(-dist[i][j]);     // dist pre-scaled by log2e
        pp[i][j] = p;
        lrow[i] += p;
      }
    }
    #pragma unroll
    for (int j = 0; j < 2; ++j) {
      float* dst = Ps + (w * 16 + kg + 8 * j) * QSTRIDE + rg * 4;
      *(float4*)dst = make_float4(pp[0][j], pp[1][j], pp[2][j], pp[3][j]);
    }
    // no barrier: PV below reads only this wave's P rows (lgkmcnt orders RAW)

    // ---- PV: O[4r][4d] += over this wave's 16 keys ----
    const int tk0 = w * 16;
    #pragma unroll 4
    for (int u = 0; u < 16; ++u) {
      const int tk = tk0 + u;
      float4 pa = *(const float4*)(Ps + tk * QSTRIDE + rg * 4);
      float4 vv = *(const float4*)(Vs + tk * QSTRIDE + kg * 4);
      O[0][0] = fmaf(pa.x, vv.x, O[0][0]); O[0][1] = fmaf(pa.x, vv.y, O[0][1]);
      O[0][2] = fmaf(pa.x, vv.z, O[0][2]); O[0][3] = fmaf(pa.x, vv.w, O[0][3]);
      O[1][0] = fmaf(pa.y, vv.x, O[1][0]); O[1][1] = fmaf(pa.y, vv.y, O[1][1]);
      O[1][2] = fmaf(pa.y, vv.z, O[1][2]); O[1][3] = fmaf(pa.y, vv.w, O[1][3]);
      O[2][0] = fmaf(pa.z, vv.x, O[2][0]); O[2][1] = fmaf(pa.z, vv.y, O[2][1]);
      O[2][2] = fmaf(pa.z, vv.z, O[2][2]); O[2][3] = fmaf(pa.z, vv.w, O[2][3]);
      O[3][0] = fmaf(pa.w, vv.x, O[3][0]); O[3][1] = fmaf(pa.w, vv.y, O[3][1]);
      O[3][2] = fmaf(pa.w, vv.z, O[3][2]); O[3][3] = fmaf(pa.w, vv.w, O[3][3]);
    }
    __syncthreads();   // DIST+PV reads done -> safe to restage K/V (and P reuse)
  }

  // ---- reduce l across kg lanes (butterfly over lane bits 0..2) ----
  #pragma unroll
  for (int i = 0; i < 4; ++i) {
    lrow[i] += __shfl_xor(lrow[i], 1);
    lrow[i] += __shfl_xor(lrow[i], 2);
    lrow[i] += __shfl_xor(lrow[i], 4);
  }

  // ---- 4-wave merge: O via Ks/Vs rows, l via Ps head ----
  float* slbuf = Ps;                 // [4][32] floats
  if (kg == 0) {
    #pragma unroll
    for (int i = 0; i < 4; ++i) slbuf[w * 32 + (rg + 8 * i)] = lrow[i];
  }
  if (w == 1) {
    #pragma unroll
    for (int i = 0; i < 4; ++i)
      *(float4*)(Ks + (rg + 8 * i) * QSTRIDE + kg * 4) =
          make_float4(O[i][0], O[i][1], O[i][2], O[i][3]);
  } else if (w == 2) {
    #pragma unroll
    for (int i = 0; i < 4; ++i)
      *(float4*)(Ks + (32 + rg + 8 * i) * QSTRIDE + kg * 4) =
          make_float4(O[i][0], O[i][1], O[i][2], O[i][3]);
  } else if (w == 3) {
    #pragma unroll
    for (int i = 0; i < 4; ++i)
      *(float4*)(Vs + (rg + 8 * i) * QSTRIDE + kg * 4) =
          make_float4(O[i][0], O[i][1], O[i][2], O[i][3]);
  }
  __syncthreads();

  if (w == 0) {
    const size_t base = (size_t)(rt * 4 + kc) * 32;
    #pragma unroll
    for (int i = 0; i < 4; ++i) {
      const int ar = rg + 8 * i;
      float4 a = *(const float4*)(Ks + ar * QSTRIDE + kg * 4);
      float4 b = *(const float4*)(Ks + (32 + ar) * QSTRIDE + kg * 4);
      float4 c = *(const float4*)(Vs + ar * QSTRIDE + kg * 4);
      float4 r;
      r.x = O[i][0] + a.x + b.x + c.x;
      r.y = O[i][1] + a.y + b.y + c.y;
      r.z = O[i][2] + a.z + b.z + c.z;
      r.w = O[i][3] + a.w + b.w + c.w;
      *(float4*)(part_o + (base + ar) * 32 + kg * 4) = r;
    }
    if (kg == 0) {
      #pragma unroll
      for (int i = 0; i < 4; ++i) {
        const int ar = rg + 8 * i;
        part_l[base + ar] = slbuf[0 * 32 + ar] + slbuf[1 * 32 + ar] +
                            slbuf[2 * 32 + ar] + slbuf[3 * 32 + ar];
      }
    }
  }
}

// ---------------------------------------------------------------------------
// Kernel C: merge kc-partials -> att rows in LDS -> out = att @ Wo^T + bo
// (R6-validated version; part layout [rt(32-row)][4 kc][32 row][32 d])
// ---------------------------------------------------------------------------
__global__ __launch_bounds__(128) void out_kernel(
    const float* __restrict__ part_o, const float* __restrict__ part_l,
    const float* __restrict__ Wo, const float* __restrict__ bo,
    float* __restrict__ out) {
  const int row0 = blockIdx.x * 8;
  const int t = threadIdx.x;

  __shared__ __align__(16) float xs[8 * E_];

  const int e = t;
  const int h = e >> 5, d = e & 31;
  #pragma unroll
  for (int i = 0; i < 8; ++i) {
    const int r = row0 + i;
    const int b = r >> 10, s = r & 1023;
    const int rt = (b * H_ + h) * 32 + (s >> 5);
    const int lrow = s & 31;
    float acc = 0.f, lsum = 0.f;
    #pragma unroll
    for (int kc = 0; kc < 4; ++kc) {
      const size_t base = (size_t)(rt * 4 + kc) * 32 + lrow;
      acc  += part_o[base * 32 + d];
      lsum += part_l[base];
    }
    xs[i * E_ + e] = acc / lsum;
  }
  __syncthreads();

  const int col = t;
  const float4* W4 = (const float4*)(Wo + (size_t)col * E_);
  const float4* xs4 = (const float4*)xs;

  float acc[8];
  #pragma unroll
  for (int r = 0; r < 8; ++r) acc[r] = 0.f;

  #pragma unroll 4
  for (int c4 = 0; c4 < E_ / 4; ++c4) {
    float4 w = W4[c4];
    #pragma unroll
    for (int r = 0; r < 8; ++r) {
      float4 xv = xs4[r * (E_ / 4) + c4];
      acc[r] += xv.x * w.x + xv.y * w.y + xv.z * w.z + xv.w * w.w;
    }
  }

  const float bcol = bo[col];
  #pragma unroll
  for (int r = 0; r < 8; ++r)
    out[(size_t)(row0 + r) * E_ + col] = acc[r] + bcol;
}

// ---------------------------------------------------------------------------
extern "C" void kernel_launch(void* const* d_in, const int* in_sizes, int n_in,
                              void* d_out, int out_size, void* d_ws, size_t ws_size,
                              hipStream_t stream) {
  const float* x  = (const float*)d_in[0];
  const float* Wq = (const float*)d_in[1];
  const float* bq = (const float*)d_in[2];
  const float* Wk = (const float*)d_in[3];
  const float* bk = (const float*)d_in[4];
  const float* Wv = (const float*)d_in[5];
  const float* bv = (const float*)d_in[6];
  const float* Wo = (const float*)d_in[7];
  const float* bo = (const float*)d_in[8];
  float* ws  = (float*)d_ws;
  float* out = (float*)d_out;

  // ws layout (floats):
  //   [0, BHSD)          q (log2e-scaled)
  //   [BHSD, 2*BHSD)     k (log2e-scaled)
  //   [2*BHSD, 3*BHSD)   v
  //   [3*BHSD, +1048576) part_o : [256 rt][4 kc][32 row][32 d]
  //   then 32768         part_l : [256 rt][4 kc][32 row]
  float* qd = ws;
  float* kd = ws + (size_t)BHSD;
  float* vd = ws + 2 * (size_t)BHSD;
  float* part_o = ws + 3 * (size_t)BHSD;
  float* part_l = part_o + (size_t)256 * 4 * 32 * 32;

  qkv_kernel<<<dim3((B_ * S_) / 8, 3), 128, 0, stream>>>(x, Wq, bq, Wk, bk, Wv, bv, ws);
  attn_kernel<<<dim3(1024), 256, 0, stream>>>(qd, kd, vd, part_o, part_l);
  out_kernel<<<dim3((B_ * S_) / 8), 128, 0, stream>>>(part_o, part_l, Wo, bo, out);
}

// Round 10
// 50.728 us; speedup vs baseline: 1.0593x; 1.0593x over previous
//
#include <hip/hip_runtime.h>
#include <hip/hip_bf16.h>

#define B_ 2
#define S_ 1024
#define E_ 128
#define H_ 4
#define D_ 32
#define BHSD (B_ * H_ * S_ * D_)   // 262144 floats per tensor
#define LOG2E 1.44269504088896f

// ---------------------------------------------------------------------------
// Kernel A: fused QKV projection (validated R5/R8 version).
//   Q and K pre-scaled by log2(e) so attention uses bare exp2.
// ---------------------------------------------------------------------------
__global__ __launch_bounds__(128) void qkv_kernel(
    const float* __restrict__ x,
    const float* __restrict__ Wq, const float* __restrict__ bq,
    const float* __restrict__ Wk, const float* __restrict__ bk,
    const float* __restrict__ Wv, const float* __restrict__ bv,
    float* __restrict__ ws) {
  const int mat = blockIdx.y;
  const float* W    = (mat == 0) ? Wq : (mat == 1) ? Wk : Wv;
  const float* bias = (mat == 0) ? bq : (mat == 1) ? bk : bv;
  const float scale = (mat == 2) ? 1.0f : LOG2E;
  float* outbase = ws + (size_t)mat * BHSD;

  const int row0 = blockIdx.x * 8;
  const int t = threadIdx.x;

  __shared__ __align__(16) float xs[8 * E_];
  const float4* xg = (const float4*)(x + (size_t)row0 * E_);
  float4* xs4 = (float4*)xs;
  #pragma unroll
  for (int i = 0; i < 2; ++i) xs4[t + i * 128] = xg[t + i * 128];
  __syncthreads();

  const int col = t;
  const float4* W4 = (const float4*)(W + (size_t)col * E_);

  float acc[8];
  #pragma unroll
  for (int r = 0; r < 8; ++r) acc[r] = 0.f;

  #pragma unroll 4
  for (int c4 = 0; c4 < E_ / 4; ++c4) {
    float4 w = W4[c4];
    #pragma unroll
    for (int r = 0; r < 8; ++r) {
      float4 xv = xs4[r * (E_ / 4) + c4];
      acc[r] += xv.x * w.x + xv.y * w.y + xv.z * w.z + xv.w * w.w;
    }
  }

  const float bcol = bias[col];
  const int h = col >> 5, d = col & 31;
  #pragma unroll
  for (int r = 0; r < 8; ++r) {
    int row = row0 + r;
    int b = row >> 10, s = row & 1023;
    outbase[(((size_t)(b * H_ + h)) * S_ + s) * D_ + d] = (acc[r] + bcol) * scale;
  }
}

// ---------------------------------------------------------------------------
// Kernel B: ultrametric attention as two register-tiled "GEMMs" (R8 structure)
// + double-buffered K/V staging with early global issue (1 barrier/iter).
//   Block = 64 Q-rows x 256 keys (kc chunk), 256 threads (4 waves).
//   Per 64-key iteration:
//     issue global loads for tile it+1 (no wait)
//     DIST: wave w keys [w*16,+16); lane (rg=lane>>3, kg=lane&7) owns
//           8 rows {rg+8i} x 2 keys {w*16+kg+8j}; dist[8][2] over 8 d-chunks.
//     p = exp2(-dist); P transposed to Ps[key][storage_row] (wave-private
//           rows [w*16,+16): no barrier needed before PV, lgkmcnt orders RAW)
//     PV:   lane (rg, kg): O[8 rows][4 dims {kg*4..}]; 16 keys; b128 reads.
//     write staged regs -> other K/V buffer; ONE barrier.
//   Dbuf safety: all waves passed the previous barrier before any wave
//   writes the next buffer (their reads of it ended one iteration ago).
// grid = 8 heads * 16 rowtiles * 4 kc = 512 blocks; LDS 62 KB -> 2 blocks/CU.
// ---------------------------------------------------------------------------
#define QSTRIDE 36
#define PSTRIDE 68
#define KBUF (64 * QSTRIDE)

__global__ __launch_bounds__(256, 2) void attn_kernel(
    const float* __restrict__ qg, const float* __restrict__ kg_,
    const float* __restrict__ vg,
    float* __restrict__ part_o, float* __restrict__ part_l) {
  __shared__ __align__(16) float Qs[64 * QSTRIDE];      //  9216 B
  __shared__ __align__(16) float Ks[2 * KBUF];          // 18432 B
  __shared__ __align__(16) float Vs[2 * KBUF];          // 18432 B
  __shared__ __align__(16) float Ps[64 * PSTRIDE];      // 17408 B (tail = l-merge)

  const int bx = blockIdx.x;
  const int kc  = bx & 3;
  const int rtl = (bx >> 2) & 15;     // row tile within head
  const int head = bx >> 6;           // b*H + h, 0..7
  const int t = threadIdx.x;
  const int w = t >> 6;               // wave 0..3
  const int lane = t & 63;
  const int rg = lane >> 3;           // row group: rows {rg + 8i}
  const int kg = lane & 7;            // key group (DIST) / dim group (PV)

  const float* qbase = qg  + (size_t)head * S_ * D_ + (size_t)rtl * 64 * D_;
  const float* kbase = kg_ + (size_t)head * S_ * D_ + (size_t)kc * 256 * D_;
  const float* vbase = vg  + (size_t)head * S_ * D_ + (size_t)kc * 256 * D_;

  const int rr0 = t >> 3, c40 = t & 7;          // staging slot for f = t
  const int rr1 = (t + 256) >> 3, c41 = t & 7;  // staging slot for f = t+256

  // ---- prologue: stage Q tile + K/V tile 0 ----
  {
    const float4* qsrc = (const float4*)qbase;
    #pragma unroll
    for (int i = 0; i < 2; ++i) {
      int f = t + i * 256;
      int rr = f >> 3, c4 = f & 7;
      *(float4*)(Qs + rr * QSTRIDE + c4 * 4) = qsrc[f];
    }
    const float4* ksrc = (const float4*)kbase;
    const float4* vsrc = (const float4*)vbase;
    *(float4*)(Ks + rr0 * QSTRIDE + c40 * 4) = ksrc[t];
    *(float4*)(Ks + rr1 * QSTRIDE + c41 * 4) = ksrc[t + 256];
    *(float4*)(Vs + rr0 * QSTRIDE + c40 * 4) = vsrc[t];
    *(float4*)(Vs + rr1 * QSTRIDE + c41 * 4) = vsrc[t + 256];
  }

  float O[8][4];
  #pragma unroll
  for (int i = 0; i < 8; ++i)
    #pragma unroll
    for (int c = 0; c < 4; ++c) O[i][c] = 0.f;
  float lrow[8];
  #pragma unroll
  for (int i = 0; i < 8; ++i) lrow[i] = 0.f;

  __syncthreads();

  #pragma unroll
  for (int it = 0; it < 4; ++it) {
    float* Kc = Ks + (it & 1) * KBUF;
    float* Vc = Vs + (it & 1) * KBUF;

    // ---- early issue: global loads for tile it+1 (latency hidden by DIST) --
    float4 nk0, nk1, nv0, nv1;
    if (it < 3) {
      const float4* ksrc = (const float4*)(kbase + (size_t)(it + 1) * 64 * D_);
      const float4* vsrc = (const float4*)(vbase + (size_t)(it + 1) * 64 * D_);
      nk0 = ksrc[t]; nk1 = ksrc[t + 256];
      nv0 = vsrc[t]; nv1 = vsrc[t + 256];
    }

    // ---- DIST: dist[8 rows][2 keys] over 8 d-chunks ----
    float dist[8][2];
    #pragma unroll
    for (int i = 0; i < 8; ++i) { dist[i][0] = 0.f; dist[i][1] = 0.f; }

    #pragma unroll 2
    for (int c = 0; c < 8; ++c) {
      float4 qv[8];
      #pragma unroll
      for (int i = 0; i < 8; ++i)
        qv[i] = *(const float4*)(Qs + (rg + 8 * i) * QSTRIDE + c * 4);
      float4 kv[2];
      #pragma unroll
      for (int j = 0; j < 2; ++j)
        kv[j] = *(const float4*)(Kc + (w * 16 + kg + 8 * j) * QSTRIDE + c * 4);
      #pragma unroll
      for (int i = 0; i < 8; ++i) {
        #pragma unroll
        for (int j = 0; j < 2; ++j) {
          float m0 = fmaxf(fabsf(qv[i].x - kv[j].x), fabsf(qv[i].y - kv[j].y));
          float m1 = fmaxf(fabsf(qv[i].z - kv[j].z), fabsf(qv[i].w - kv[j].w));
          dist[i][j] = fmaxf(dist[i][j], fmaxf(m0, m1));
        }
      }
    }

    // ---- p = exp2(-dist); accumulate l; write P transposed (wave-private) --
    float pp[8][2];
    #pragma unroll
    for (int i = 0; i < 8; ++i) {
      #pragma unroll
      for (int j = 0; j < 2; ++j) {
        float p = exp2f(-dist[i][j]);     // dist pre-scaled by log2e
        pp[i][j] = p;
        lrow[i] += p;
      }
    }
    #pragma unroll
    for (int j = 0; j < 2; ++j) {
      float* dst = Ps + (w * 16 + kg + 8 * j) * PSTRIDE + rg * 8;
      *(float4*)(dst + 0) = make_float4(pp[0][j], pp[1][j], pp[2][j], pp[3][j]);
      *(float4*)(dst + 4) = make_float4(pp[4][j], pp[5][j], pp[6][j], pp[7][j]);
    }
    // no barrier: PV reads only this wave's P rows (lgkmcnt orders RAW)

    // ---- PV: O[8r][4d] += over this wave's 16 keys ----
    const int tk0 = w * 16;
    #pragma unroll 4
    for (int u = 0; u < 16; ++u) {
      const int tk = tk0 + u;
      float4 pa = *(const float4*)(Ps + tk * PSTRIDE + rg * 8);
      float4 pb = *(const float4*)(Ps + tk * PSTRIDE + rg * 8 + 4);
      float4 vv = *(const float4*)(Vc + tk * QSTRIDE + kg * 4);
      O[0][0] = fmaf(pa.x, vv.x, O[0][0]); O[0][1] = fmaf(pa.x, vv.y, O[0][1]);
      O[0][2] = fmaf(pa.x, vv.z, O[0][2]); O[0][3] = fmaf(pa.x, vv.w, O[0][3]);
      O[1][0] = fmaf(pa.y, vv.x, O[1][0]); O[1][1] = fmaf(pa.y, vv.y, O[1][1]);
      O[1][2] = fmaf(pa.y, vv.z, O[1][2]); O[1][3] = fmaf(pa.y, vv.w, O[1][3]);
      O[2][0] = fmaf(pa.z, vv.x, O[2][0]); O[2][1] = fmaf(pa.z, vv.y, O[2][1]);
      O[2][2] = fmaf(pa.z, vv.z, O[2][2]); O[2][3] = fmaf(pa.z, vv.w, O[2][3]);
      O[3][0] = fmaf(pa.w, vv.x, O[3][0]); O[3][1] = fmaf(pa.w, vv.y, O[3][1]);
      O[3][2] = fmaf(pa.w, vv.z, O[3][2]); O[3][3] = fmaf(pa.w, vv.w, O[3][3]);
      O[4][0] = fmaf(pb.x, vv.x, O[4][0]); O[4][1] = fmaf(pb.x, vv.y, O[4][1]);
      O[4][2] = fmaf(pb.x, vv.z, O[4][2]); O[4][3] = fmaf(pb.x, vv.w, O[4][3]);
      O[5][0] = fmaf(pb.y, vv.x, O[5][0]); O[5][1] = fmaf(pb.y, vv.y, O[5][1]);
      O[5][2] = fmaf(pb.y, vv.z, O[5][2]); O[5][3] = fmaf(pb.y, vv.w, O[5][3]);
      O[6][0] = fmaf(pb.z, vv.x, O[6][0]); O[6][1] = fmaf(pb.z, vv.y, O[6][1]);
      O[6][2] = fmaf(pb.z, vv.z, O[6][2]); O[6][3] = fmaf(pb.z, vv.w, O[6][3]);
      O[7][0] = fmaf(pb.w, vv.x, O[7][0]); O[7][1] = fmaf(pb.w, vv.y, O[7][1]);
      O[7][2] = fmaf(pb.w, vv.z, O[7][2]); O[7][3] = fmaf(pb.w, vv.w, O[7][3]);
    }

    // ---- write staged regs into the other buffer, then the ONE barrier ----
    if (it < 3) {
      float* Kn = Ks + ((it + 1) & 1) * KBUF;
      float* Vn = Vs + ((it + 1) & 1) * KBUF;
      *(float4*)(Kn + rr0 * QSTRIDE + c40 * 4) = nk0;
      *(float4*)(Kn + rr1 * QSTRIDE + c41 * 4) = nk1;
      *(float4*)(Vn + rr0 * QSTRIDE + c40 * 4) = nv0;
      *(float4*)(Vn + rr1 * QSTRIDE + c41 * 4) = nv1;
    }
    __syncthreads();
  }

  // ---- reduce l across kg lanes (butterfly over lane bits 0..2) ----
  #pragma unroll
  for (int i = 0; i < 8; ++i) {
    lrow[i] += __shfl_xor(lrow[i], 1);
    lrow[i] += __shfl_xor(lrow[i], 2);
    lrow[i] += __shfl_xor(lrow[i], 4);
  }

  // ---- 4-wave O merge reusing LDS buffers; l via Ps tail ----
  float* slbuf = Ps + 64 * 64;        // 256 floats, disjoint from [64][..64) use
  if (kg == 0) {
    #pragma unroll
    for (int i = 0; i < 8; ++i) slbuf[w * 64 + (rg + 8 * i)] = lrow[i];
  }
  if (w == 1) {
    #pragma unroll
    for (int i = 0; i < 8; ++i)
      *(float4*)(Ks + (rg + 8 * i) * QSTRIDE + kg * 4) =
          make_float4(O[i][0], O[i][1], O[i][2], O[i][3]);
  } else if (w == 2) {
    #pragma unroll
    for (int i = 0; i < 8; ++i)
      *(float4*)(Vs + (rg + 8 * i) * QSTRIDE + kg * 4) =
          make_float4(O[i][0], O[i][1], O[i][2], O[i][3]);
  } else if (w == 3) {
    #pragma unroll
    for (int i = 0; i < 8; ++i)
      *(float4*)(Qs + (rg + 8 * i) * QSTRIDE + kg * 4) =
          make_float4(O[i][0], O[i][1], O[i][2], O[i][3]);
  }
  __syncthreads();

  if (w == 0) {
    const size_t base = ((size_t)(head * 16 + rtl) * 4 + kc) * 64;
    #pragma unroll
    for (int i = 0; i < 8; ++i) {
      const int ar = rg + 8 * i;
      float4 a = *(const float4*)(Ks + ar * QSTRIDE + kg * 4);
      float4 b = *(const float4*)(Vs + ar * QSTRIDE + kg * 4);
      float4 c = *(const float4*)(Qs + ar * QSTRIDE + kg * 4);
      float4 r;
      r.x = O[i][0] + a.x + b.x + c.x;
      r.y = O[i][1] + a.y + b.y + c.y;
      r.z = O[i][2] + a.z + b.z + c.z;
      r.w = O[i][3] + a.w + b.w + c.w;
      *(float4*)(part_o + (base + ar) * 32 + kg * 4) = r;
    }
    if (kg == 0) {
      #pragma unroll
      for (int i = 0; i < 8; ++i) {
        const int ar = rg + 8 * i;
        part_l[base + ar] = slbuf[0 * 64 + ar] + slbuf[1 * 64 + ar] +
                            slbuf[2 * 64 + ar] + slbuf[3 * 64 + ar];
      }
    }
  }
}

// ---------------------------------------------------------------------------
// Kernel C: merge kc-partials -> att rows in LDS -> out = att @ Wo^T + bo
// (R3/R8-validated; part layout [rt(64-row)][4 kc][64 row][32 d])
// ---------------------------------------------------------------------------
__global__ __launch_bounds__(128) void out_kernel(
    const float* __restrict__ part_o, const float* __restrict__ part_l,
    const float* __restrict__ Wo, const float* __restrict__ bo,
    float* __restrict__ out) {
  const int row0 = blockIdx.x * 8;
  const int t = threadIdx.x;

  __shared__ __align__(16) float xs[8 * E_];

  const int e = t;
  const int h = e >> 5, d = e & 31;
  #pragma unroll
  for (int i = 0; i < 8; ++i) {
    const int r = row0 + i;
    const int b = r >> 10, s = r & 1023;
    const int rt = (b * H_ + h) * 16 + (s >> 6);
    const int lrow = s & 63;
    float acc = 0.f, lsum = 0.f;
    #pragma unroll
    for (int kc = 0; kc < 4; ++kc) {
      const size_t base = (size_t)(rt * 4 + kc) * 64 + lrow;
      acc  += part_o[base * 32 + d];
      lsum += part_l[base];
    }
    xs[i * E_ + e] = acc / lsum;
  }
  __syncthreads();

  const int col = t;
  const float4* W4 = (const float4*)(Wo + (size_t)col * E_);
  const float4* xs4 = (const float4*)xs;

  float acc[8];
  #pragma unroll
  for (int r = 0; r < 8; ++r) acc[r] = 0.f;

  #pragma unroll 4
  for (int c4 = 0; c4 < E_ / 4; ++c4) {
    float4 w = W4[c4];
    #pragma unroll
    for (int r = 0; r < 8; ++r) {
      float4 xv = xs4[r * (E_ / 4) + c4];
      acc[r] += xv.x * w.x + xv.y * w.y + xv.z * w.z + xv.w * w.w;
    }
  }

  const float bcol = bo[col];
  #pragma unroll
  for (int r = 0; r < 8; ++r)
    out[(size_t)(row0 + r) * E_ + col] = acc[r] + bcol;
}

// ---------------------------------------------------------------------------
extern "C" void kernel_launch(void* const* d_in, const int* in_sizes, int n_in,
                              void* d_out, int out_size, void* d_ws, size_t ws_size,
                              hipStream_t stream) {
  const float* x  = (const float*)d_in[0];
  const float* Wq = (const float*)d_in[1];
  const float* bq = (const float*)d_in[2];
  const float* Wk = (const float*)d_in[3];
  const float* bk = (const float*)d_in[4];
  const float* Wv = (const float*)d_in[5];
  const float* bv = (const float*)d_in[6];
  const float* Wo = (const float*)d_in[7];
  const float* bo = (const float*)d_in[8];
  float* ws  = (float*)d_ws;
  float* out = (float*)d_out;

  // ws layout (floats):
  //   [0, BHSD)          q (log2e-scaled)
  //   [BHSD, 2*BHSD)     k (log2e-scaled)
  //   [2*BHSD, 3*BHSD)   v
  //   [3*BHSD, +1048576) part_o : [128 rt][4 kc][64 row][32 d]
  //   then 32768         part_l : [128 rt][4 kc][64 row]
  float* qd = ws;
  float* kd = ws + (size_t)BHSD;
  float* vd = ws + 2 * (size_t)BHSD;
  float* part_o = ws + 3 * (size_t)BHSD;
  float* part_l = part_o + (size_t)128 * 4 * 64 * 32;

  qkv_kernel<<<dim3((B_ * S_) / 8, 3), 128, 0, stream>>>(x, Wq, bq, Wk, bk, Wv, bv, ws);
  attn_kernel<<<dim3(512), 256, 0, stream>>>(qd, kd, vd, part_o, part_l);
  out_kernel<<<dim3((B_ * S_) / 8), 128, 0, stream>>>(part_o, part_l, Wo, bo, out);
}